// Round 2
// baseline (289.741 us; speedup 1.0000x reference)
//
#include <hip/hip_runtime.h>

// ConvCaps EM routing, MI355X.
// Geometry: b=16, H=W=14, B_IN=32, P=4 (PSIZE=16), K=3, stride=2 -> oh=ow=6.
// N = K*K*B_IN = 288 input capsules per position, C_OUT = 32, ITERS = 3.
// One block per output position (576 blocks), 512 threads (8 waves).
// Per step each half-wave owns one n; lane&31 = output capsule c; thread holds all 16 il.
// 8 waves * 18 steps * 2 halves = 288 n.

#define NB 288
#define NSTEP 18
#define LN2PI 1.8378770664093453f

__global__ __launch_bounds__(512, 6)
void convcaps_em(const float* __restrict__ x,
                 const float* __restrict__ a,
                 const float* __restrict__ W,
                 const float* __restrict__ bu,
                 const float* __restrict__ ba,
                 float* __restrict__ out)
{
    __shared__ __align__(16) float pose_s[NB * 16];   // 18432 B
    __shared__ __align__(16) float ain_s[NB];         //  1152 B
    __shared__             float S1w[4][32][17];      //  8704 B (padded: conflict-free)
    __shared__             float S2w[4][32][17];      //  8704 B
    __shared__             float Rw[8][32];           //  1024 B
    __shared__             float mu_s[32][17];        //  2176 B
    __shared__             float p_s[32][17];         //  2176 B
    __shared__             float A_s[32];             //   128 B
    // total ~42.5 KB -> 3 blocks/CU; 576 blocks all co-resident (<= 768 slots)

    const int tid  = threadIdx.x;
    const int wv   = tid >> 6;          // wave 0..7
    const int lane = tid & 63;
    const int half = (lane >> 5) & 1;   // which n of the pair
    const int c    = lane & 31;         // output capsule

    const int bid = blockIdx.x;         // b*36 + oy*6 + ox
    const int b   = bid / 36;
    const int rem = bid % 36;
    const int oy  = rem / 6, ox = rem % 6;
    const int iy0 = oy * 2, ix0 = ox * 2;

    // ---- stage pose patch (9 x 512 floats) and a patch (9 x 32 floats) into LDS ----
    {
        const float4* x4 = (const float4*)x;
        float4* d4 = (float4*)pose_s;
        #pragma unroll
        for (int i = 0; i < 3; ++i) {
            int idx = tid + i * 512;
            if (idx < 1152) {                       // 9 segs * 128 float4
                int seg = idx >> 7, u = idx & 127;
                int kh = seg / 3, kw = seg % 3;
                d4[idx] = x4[((b * 14 + iy0 + kh) * 14 + (ix0 + kw)) * 128 + u];
            }
        }
        const float4* a4 = (const float4*)a;
        float4* e4 = (float4*)ain_s;
        if (tid < 72) {                             // 9 segs * 8 float4
            int seg = tid >> 3, u = tid & 7;
            int kh = seg / 3, kw = seg % 3;
            e4[tid] = a4[((b * 14 + iy0 + kh) * 14 + (ix0 + kw)) * 8 + u];
        }
    }
    __syncthreads();

    const float4* W4 = (const float4*)W;

    float muh[16], ph[16];
    float Ac = 0.0f;
    #pragma unroll
    for (int i = 0; i < 16; ++i) { muh[i] = 0.0f; ph[i] = 0.0f; }

    for (int iter = 0; iter < 3; ++iter) {
        // hoist per-c E-step constants from previous finalize (stride-17: conflict-free)
        if (iter > 0) {
            #pragma unroll
            for (int il = 0; il < 16; ++il) {
                muh[il] = mu_s[c][il];
                ph[il]  = p_s[c][il];
            }
            Ac = A_s[c];
        }

        float S1[16], S2[16];
        #pragma unroll
        for (int i = 0; i < 16; ++i) { S1[i] = 0.0f; S2[i] = 0.0f; }
        float Racc = 0.0f;

        for (int s = 0; s < NSTEP; ++s) {
            const int n = wv * 36 + 2 * s + half;

            // load W[n][c][0..15] (coalesced: half-wave reads contiguous 2KB slice)
            float wreg[16], preg[16];
            {
                const float4* wp = W4 + (size_t)(n * 32 + c) * 4;
                float4 w0 = wp[0], w1 = wp[1], w2 = wp[2], w3 = wp[3];
                wreg[0]=w0.x; wreg[1]=w0.y; wreg[2]=w0.z; wreg[3]=w0.w;
                wreg[4]=w1.x; wreg[5]=w1.y; wreg[6]=w1.z; wreg[7]=w1.w;
                wreg[8]=w2.x; wreg[9]=w2.y; wreg[10]=w2.z; wreg[11]=w2.w;
                wreg[12]=w3.x; wreg[13]=w3.y; wreg[14]=w3.z; wreg[15]=w3.w;
                const float4* pp = (const float4*)&pose_s[n * 16];
                float4 p0 = pp[0], p1 = pp[1], p2 = pp[2], p3 = pp[3];
                preg[0]=p0.x; preg[1]=p0.y; preg[2]=p0.z; preg[3]=p0.w;
                preg[4]=p1.x; preg[5]=p1.y; preg[6]=p1.z; preg[7]=p1.w;
                preg[8]=p2.x; preg[9]=p2.y; preg[10]=p2.z; preg[11]=p2.w;
                preg[12]=p3.x; preg[13]=p3.y; preg[14]=p3.z; preg[15]=p3.w;
            }

            // v[i*4+l] = sum_j pose[i*4+j] * W[j*4+l]   (4x4 matmul)
            float v[16];
            #pragma unroll
            for (int i = 0; i < 4; ++i) {
                #pragma unroll
                for (int l = 0; l < 4; ++l) {
                    float acc = preg[i*4+0] * wreg[l];
                    acc = fmaf(preg[i*4+1], wreg[4 + l], acc);
                    acc = fmaf(preg[i*4+2], wreg[8 + l], acc);
                    acc = fmaf(preg[i*4+3], wreg[12 + l], acc);
                    v[i*4+l] = acc;
                }
            }

            float r;
            if (iter == 0) {
                r = ain_s[n] * 0.03125f;            // a_in / C
            } else {
                // ln_ap[n,c] = A_c - sum_il p*(v-mu)^2
                float acc = 0.0f;
                #pragma unroll
                for (int il = 0; il < 16; ++il) {
                    float d = v[il] - muh[il];
                    acc = fmaf(-ph[il], d * d, acc);
                }
                float lnap = Ac + acc;
                // softmax over the 32 lanes of this half-wave (axis c)
                float m = lnap;
                #pragma unroll
                for (int mk = 16; mk >= 1; mk >>= 1)
                    m = fmaxf(m, __shfl_xor(m, mk));
                float e = __expf(lnap - m);
                float ssum = e;
                #pragma unroll
                for (int mk = 16; mk >= 1; mk >>= 1)
                    ssum += __shfl_xor(ssum, mk);
                r = __fdividef(e, ssum);
            }

            Racc += r;
            #pragma unroll
            for (int il = 0; il < 16; ++il) {
                float rv = r * v[il];
                S1[il] += rv;
                S2[il] = fmaf(rv, v[il], S2[il]);
            }
        }

        // combine the two half-wave partials (same c, disjoint n)
        #pragma unroll
        for (int il = 0; il < 16; ++il) {
            S1[il] += __shfl_xor(S1[il], 32);
            S2[il] += __shfl_xor(S2[il], 32);
        }
        Racc += __shfl_xor(Racc, 32);

        // two-phase wave reduction; halves split S1/S2 LDS traffic
        if (wv >= 4) {
            if (half == 0) {
                #pragma unroll
                for (int il = 0; il < 16; ++il) S1w[wv - 4][c][il] = S1[il];
            } else {
                #pragma unroll
                for (int il = 0; il < 16; ++il) S2w[wv - 4][c][il] = S2[il];
            }
        }
        if (half == 0) Rw[wv][c] = Racc;
        __syncthreads();
        if (wv < 4) {
            if (half == 0) {
                #pragma unroll
                for (int il = 0; il < 16; ++il) S1w[wv][c][il] += S1[il];
            } else {
                #pragma unroll
                for (int il = 0; il < 16; ++il) S2w[wv][c][il] += S2[il];
            }
        }
        __syncthreads();

        // ---- finalize M-step: thread t = c2*16 + k handles il = k ----
        {
            const int c2 = tid >> 4, k = tid & 15;
            float R = 0.0f;
            #pragma unroll
            for (int w = 0; w < 8; ++w) R += Rw[w][c2];
            float rinv = __fdividef(1.0f, R + 1e-8f);

            float s1 = S1w[0][c2][k] + S1w[1][c2][k] + S1w[2][c2][k] + S1w[3][c2][k];
            float s2 = S2w[0][c2][k] + S2w[1][c2][k] + S2w[2][c2][k] + S2w[3][c2][k];
            float mu  = s1 * rinv;
            float sig = fmaf(-mu, mu, s2 * rinv);
            sig = fmaxf(sig, 1e-30f);
            float pv  = __fdividef(0.5f, sig);       // 1/(2*sigma^2)
            float tpart = __logf(sig);
            #pragma unroll
            for (int mk = 8; mk >= 1; mk >>= 1)
                tpart += __shfl_xor(tpart, mk);      // sum over 16 il

            float cost = R * fmaf(0.5f, tpart, 16.0f * bu[c2]);
            float aout = __fdividef(1.0f, 1.0f + __expf(-(0.001f * (ba[c2] - cost))));

            if (iter < 2) {
                mu_s[c2][k] = mu;
                p_s[c2][k]  = pv;
                if (k == 0)
                    A_s[c2] = __logf(aout) - 0.5f * tpart - 8.0f * LN2PI;
            } else {
                out[(size_t)bid * 512 + c2 * 16 + k] = mu;
                if (k == 0)
                    out[294912 + bid * 32 + c2] = aout;
            }
        }
        __syncthreads();
    }
}

extern "C" void kernel_launch(void* const* d_in, const int* in_sizes, int n_in,
                              void* d_out, int out_size, void* d_ws, size_t ws_size,
                              hipStream_t stream) {
    (void)in_sizes; (void)n_in; (void)d_ws; (void)ws_size; (void)out_size;
    const float* x  = (const float*)d_in[0];
    const float* a  = (const float*)d_in[1];
    const float* w  = (const float*)d_in[2];
    const float* bu = (const float*)d_in[3];
    const float* ba = (const float*)d_in[4];
    float* out = (float*)d_out;
    hipLaunchKernelGGL(convcaps_em, dim3(576), dim3(512), 0, stream,
                       x, a, w, bu, ba, out);
}

// Round 3
// 135.603 us; speedup vs baseline: 2.1367x; 2.1367x over previous
//
#include <hip/hip_runtime.h>

// ConvCaps EM routing, MI355X.
// Geometry: b=16, H=W=14, B_IN=32, P=4 (PSIZE=16), K=3, stride=2 -> oh=ow=6.
// N = K*K*B_IN = 288 input capsules per position, C_OUT = 32, ITERS = 3.
// One block per output position (576 blocks), 512 threads (8 waves).
// Per step each half-wave owns one n; lane&31 = output capsule c; thread holds all 16 il.
// 8 waves * 18 steps * 2 halves = 288 n.
//
// R2 lesson: __launch_bounds__(512,6) capped VGPR at 40 -> full spill of the
// ~112-float per-thread state (FETCH 7.8MB -> 460MB). No min-waves cap here;
// compiler's natural allocation (~80-110 VGPR) still gives ~4 waves/SIMD.

#define NB 288
#define NSTEP 18
#define LN2PI 1.8378770664093453f

__global__ __launch_bounds__(512)
void convcaps_em(const float* __restrict__ x,
                 const float* __restrict__ a,
                 const float* __restrict__ W,
                 const float* __restrict__ bu,
                 const float* __restrict__ ba,
                 float* __restrict__ out)
{
    __shared__ __align__(16) float pose_s[NB * 16];   // 18432 B
    __shared__ __align__(16) float ain_s[NB];         //  1152 B
    __shared__             float S1w[4][32][17];      //  8704 B (padded: conflict-free)
    __shared__             float S2w[4][32][17];      //  8704 B
    __shared__             float Rw[8][32];           //  1024 B
    __shared__             float mu_s[32][17];        //  2176 B
    __shared__             float p_s[32][17];         //  2176 B
    __shared__             float A_s[32];             //   128 B
    // total ~42.5 KB -> 3 blocks/CU possible; grid (576) limits to ~2.25 blocks/CU

    const int tid  = threadIdx.x;
    const int wv   = tid >> 6;          // wave 0..7
    const int lane = tid & 63;
    const int half = (lane >> 5) & 1;   // which n of the pair
    const int c    = lane & 31;         // output capsule

    const int bid = blockIdx.x;         // b*36 + oy*6 + ox
    const int b   = bid / 36;
    const int rem = bid % 36;
    const int oy  = rem / 6, ox = rem % 6;
    const int iy0 = oy * 2, ix0 = ox * 2;

    // ---- stage pose patch (9 x 512 floats) and a patch (9 x 32 floats) into LDS ----
    {
        const float4* x4 = (const float4*)x;
        float4* d4 = (float4*)pose_s;
        #pragma unroll
        for (int i = 0; i < 3; ++i) {
            int idx = tid + i * 512;
            if (idx < 1152) {                       // 9 segs * 128 float4
                int seg = idx >> 7, u = idx & 127;
                int kh = seg / 3, kw = seg % 3;
                d4[idx] = x4[((b * 14 + iy0 + kh) * 14 + (ix0 + kw)) * 128 + u];
            }
        }
        const float4* a4 = (const float4*)a;
        float4* e4 = (float4*)ain_s;
        if (tid < 72) {                             // 9 segs * 8 float4
            int seg = tid >> 3, u = tid & 7;
            int kh = seg / 3, kw = seg % 3;
            e4[tid] = a4[((b * 14 + iy0 + kh) * 14 + (ix0 + kw)) * 8 + u];
        }
    }
    __syncthreads();

    const float4* W4 = (const float4*)W;

    float muh[16], ph[16];
    float Ac = 0.0f;
    #pragma unroll
    for (int i = 0; i < 16; ++i) { muh[i] = 0.0f; ph[i] = 0.0f; }

    for (int iter = 0; iter < 3; ++iter) {
        // hoist per-c E-step constants from previous finalize (stride-17: conflict-free)
        if (iter > 0) {
            #pragma unroll
            for (int il = 0; il < 16; ++il) {
                muh[il] = mu_s[c][il];
                ph[il]  = p_s[c][il];
            }
            Ac = A_s[c];
        }

        float S1[16], S2[16];
        #pragma unroll
        for (int i = 0; i < 16; ++i) { S1[i] = 0.0f; S2[i] = 0.0f; }
        float Racc = 0.0f;

        for (int s = 0; s < NSTEP; ++s) {
            const int n = wv * 36 + 2 * s + half;

            // load W[n][c][0..15] (coalesced: half-wave reads contiguous 2KB slice)
            float wreg[16], preg[16];
            {
                const float4* wp = W4 + (size_t)(n * 32 + c) * 4;
                float4 w0 = wp[0], w1 = wp[1], w2 = wp[2], w3 = wp[3];
                wreg[0]=w0.x; wreg[1]=w0.y; wreg[2]=w0.z; wreg[3]=w0.w;
                wreg[4]=w1.x; wreg[5]=w1.y; wreg[6]=w1.z; wreg[7]=w1.w;
                wreg[8]=w2.x; wreg[9]=w2.y; wreg[10]=w2.z; wreg[11]=w2.w;
                wreg[12]=w3.x; wreg[13]=w3.y; wreg[14]=w3.z; wreg[15]=w3.w;
                const float4* pp = (const float4*)&pose_s[n * 16];
                float4 p0 = pp[0], p1 = pp[1], p2 = pp[2], p3 = pp[3];
                preg[0]=p0.x; preg[1]=p0.y; preg[2]=p0.z; preg[3]=p0.w;
                preg[4]=p1.x; preg[5]=p1.y; preg[6]=p1.z; preg[7]=p1.w;
                preg[8]=p2.x; preg[9]=p2.y; preg[10]=p2.z; preg[11]=p2.w;
                preg[12]=p3.x; preg[13]=p3.y; preg[14]=p3.z; preg[15]=p3.w;
            }

            // v[i*4+l] = sum_j pose[i*4+j] * W[j*4+l]   (4x4 matmul)
            float v[16];
            #pragma unroll
            for (int i = 0; i < 4; ++i) {
                #pragma unroll
                for (int l = 0; l < 4; ++l) {
                    float acc = preg[i*4+0] * wreg[l];
                    acc = fmaf(preg[i*4+1], wreg[4 + l], acc);
                    acc = fmaf(preg[i*4+2], wreg[8 + l], acc);
                    acc = fmaf(preg[i*4+3], wreg[12 + l], acc);
                    v[i*4+l] = acc;
                }
            }

            float r;
            if (iter == 0) {
                r = ain_s[n] * 0.03125f;            // a_in / C
            } else {
                // ln_ap[n,c] = A_c - sum_il p*(v-mu)^2
                float acc = 0.0f;
                #pragma unroll
                for (int il = 0; il < 16; ++il) {
                    float d = v[il] - muh[il];
                    acc = fmaf(-ph[il], d * d, acc);
                }
                float lnap = Ac + acc;
                // softmax over the 32 lanes of this half-wave (axis c)
                float m = lnap;
                #pragma unroll
                for (int mk = 16; mk >= 1; mk >>= 1)
                    m = fmaxf(m, __shfl_xor(m, mk));
                float e = __expf(lnap - m);
                float ssum = e;
                #pragma unroll
                for (int mk = 16; mk >= 1; mk >>= 1)
                    ssum += __shfl_xor(ssum, mk);
                r = __fdividef(e, ssum);
            }

            Racc += r;
            #pragma unroll
            for (int il = 0; il < 16; ++il) {
                float rv = r * v[il];
                S1[il] += rv;
                S2[il] = fmaf(rv, v[il], S2[il]);
            }
        }

        // combine the two half-wave partials (same c, disjoint n)
        #pragma unroll
        for (int il = 0; il < 16; ++il) {
            S1[il] += __shfl_xor(S1[il], 32);
            S2[il] += __shfl_xor(S2[il], 32);
        }
        Racc += __shfl_xor(Racc, 32);

        // two-phase wave reduction; halves split S1/S2 LDS traffic
        if (wv >= 4) {
            if (half == 0) {
                #pragma unroll
                for (int il = 0; il < 16; ++il) S1w[wv - 4][c][il] = S1[il];
            } else {
                #pragma unroll
                for (int il = 0; il < 16; ++il) S2w[wv - 4][c][il] = S2[il];
            }
        }
        if (half == 0) Rw[wv][c] = Racc;
        __syncthreads();
        if (wv < 4) {
            if (half == 0) {
                #pragma unroll
                for (int il = 0; il < 16; ++il) S1w[wv][c][il] += S1[il];
            } else {
                #pragma unroll
                for (int il = 0; il < 16; ++il) S2w[wv][c][il] += S2[il];
            }
        }
        __syncthreads();

        // ---- finalize M-step: thread t = c2*16 + k handles il = k ----
        {
            const int c2 = tid >> 4, k = tid & 15;
            float R = 0.0f;
            #pragma unroll
            for (int w = 0; w < 8; ++w) R += Rw[w][c2];
            float rinv = __fdividef(1.0f, R + 1e-8f);

            float s1 = S1w[0][c2][k] + S1w[1][c2][k] + S1w[2][c2][k] + S1w[3][c2][k];
            float s2 = S2w[0][c2][k] + S2w[1][c2][k] + S2w[2][c2][k] + S2w[3][c2][k];
            float mu  = s1 * rinv;
            float sig = fmaf(-mu, mu, s2 * rinv);
            sig = fmaxf(sig, 1e-30f);
            float pv  = __fdividef(0.5f, sig);       // 1/(2*sigma^2)
            float tpart = __logf(sig);
            #pragma unroll
            for (int mk = 8; mk >= 1; mk >>= 1)
                tpart += __shfl_xor(tpart, mk);      // sum over 16 il

            float cost = R * fmaf(0.5f, tpart, 16.0f * bu[c2]);
            float aout = __fdividef(1.0f, 1.0f + __expf(-(0.001f * (ba[c2] - cost))));

            if (iter < 2) {
                mu_s[c2][k] = mu;
                p_s[c2][k]  = pv;
                if (k == 0)
                    A_s[c2] = __logf(aout) - 0.5f * tpart - 8.0f * LN2PI;
            } else {
                out[(size_t)bid * 512 + c2 * 16 + k] = mu;
                if (k == 0)
                    out[294912 + bid * 32 + c2] = aout;
            }
        }
        __syncthreads();
    }
}

extern "C" void kernel_launch(void* const* d_in, const int* in_sizes, int n_in,
                              void* d_out, int out_size, void* d_ws, size_t ws_size,
                              hipStream_t stream) {
    (void)in_sizes; (void)n_in; (void)d_ws; (void)ws_size; (void)out_size;
    const float* x  = (const float*)d_in[0];
    const float* a  = (const float*)d_in[1];
    const float* w  = (const float*)d_in[2];
    const float* bu = (const float*)d_in[3];
    const float* ba = (const float*)d_in[4];
    float* out = (float*)d_out;
    hipLaunchKernelGGL(convcaps_em, dim3(576), dim3(512), 0, stream,
                       x, a, w, bu, ba, out);
}

// Round 4
// 123.187 us; speedup vs baseline: 2.3520x; 1.1008x over previous
//
#include <hip/hip_runtime.h>

// ConvCaps EM routing, MI355X — multi-dispatch version.
// Geometry: b=16 -> oh=ow=6 -> 576 positions; N=288 input caps; C=32; ITERS=3.
//
// R1 (1 block/pos, 4 waves): 107us, VALUBusy 40%, Occ 20% -> latency/imbalance-bound.
// R3 (8 waves/block): 135us — bigger blocks reduced occupancy & added convoys.
// R4: split n into NCH=4 chunks -> 2304 blocks/pass, 3 M-pass dispatches
// (stream order = iteration sync), partial S1/S2/R in ws (parity double-buffer),
// finalize fused redundantly into the next pass. Deterministic (no atomics).

#define LN2PI 1.8378770664093453f

// ---------------- M-pass kernel ----------------
// grid (576, NCH), block 256 (4 waves). pos=blockIdx.x, chunk=blockIdx.y.
// Each half-wave owns one n per step; lane&31 = output capsule c.
template<int NCH, bool FIRST>
__global__ __launch_bounds__(256)
void em_pass(const float* __restrict__ x,
             const float* __restrict__ a,
             const float* __restrict__ W,
             const float* __restrict__ bu,
             const float* __restrict__ ba,
             const float* __restrict__ part_r,
             float* __restrict__ part_w)
{
    constexpr int NCAP  = 288 / NCH;     // n's per chunk
    constexpr int NSTEP = NCAP / 8;      // 4 waves * 2 halves
    constexpr int SZ_S  = 576 * NCH * 32 * 16;

    __shared__ __align__(16) float pose_s[NCAP * 16];
    __shared__ float ain_s[FIRST ? NCAP : 1];
    __shared__ float S1w[4][32][17];
    __shared__ float S2w[4][32][17];
    __shared__ float Rw[4][32];
    __shared__ float mu_s[32][17];
    __shared__ float p_s[32][17];
    __shared__ float A_s[32];

    const int tid  = threadIdx.x;
    const int wv   = tid >> 6;
    const int lane = tid & 63;
    const int half = (lane >> 5) & 1;
    const int c    = lane & 31;

    const int pos = blockIdx.x;          // b*36 + oy*6 + ox
    const int ch  = blockIdx.y;
    const int b   = pos / 36;
    const int rem = pos % 36;
    const int oy  = rem / 6, ox = rem % 6;
    const int iy0 = oy * 2, ix0 = ox * 2;

    // ---- stage pose chunk (NCAP x 16 floats) into LDS ----
    {
        const float4* x4 = (const float4*)x;
        float4* d4 = (float4*)pose_s;
        for (int idx = tid; idx < NCAP * 4; idx += 256) {
            int n_l = idx >> 2, j = idx & 3;
            int n_g = ch * NCAP + n_l;
            int seg = n_g >> 5, bi = n_g & 31;
            int kh = seg / 3, kw = seg % 3;
            d4[idx] = x4[((b * 14 + iy0 + kh) * 14 + (ix0 + kw)) * 128 + bi * 4 + j];
        }
        if constexpr (FIRST) {
            for (int idx = tid; idx < NCAP; idx += 256) {
                int n_g = ch * NCAP + idx;
                int seg = n_g >> 5, bi = n_g & 31;
                int kh = seg / 3, kw = seg % 3;
                ain_s[idx] = a[((b * 14 + iy0 + kh) * 14 + (ix0 + kw)) * 32 + bi];
            }
        }
    }

    if constexpr (!FIRST) {
        // ---- fused finalize of the PREVIOUS pass's partials -> mu/p/A in LDS.
        // Redundant per chunk-block (tiny). thread = cf*8 + k2, handles il=k2,k2+8.
        const int cf = tid >> 3, k2 = tid & 7;
        float R = 0.f;
        #pragma unroll
        for (int q = 0; q < NCH; ++q)
            R += part_r[2 * SZ_S + (pos * NCH + q) * 32 + cf];
        float rinv = __fdividef(1.f, R + 1e-8f);
        float muv[2], pv[2];
        float tpart = 0.f;
        #pragma unroll
        for (int t2 = 0; t2 < 2; ++t2) {
            int k = k2 + t2 * 8;
            int base = ((pos * NCH) * 32 + cf) * 16 + k;
            float s1 = 0.f, s2 = 0.f;
            #pragma unroll
            for (int q = 0; q < NCH; ++q) {
                s1 += part_r[base + q * 512];
                s2 += part_r[SZ_S + base + q * 512];
            }
            float mu  = s1 * rinv;
            float sig = fmaf(-mu, mu, s2 * rinv);
            sig = fmaxf(sig, 1e-30f);
            muv[t2] = mu;
            pv[t2]  = __fdividef(0.5f, sig);
            tpart  += __logf(sig);
        }
        #pragma unroll
        for (int mk = 4; mk >= 1; mk >>= 1)
            tpart += __shfl_xor(tpart, mk);
        float cost = R * fmaf(0.5f, tpart, 16.f * bu[cf]);
        float aout = __fdividef(1.f, 1.f + __expf(-(0.001f * (ba[cf] - cost))));
        mu_s[cf][k2]     = muv[0];
        mu_s[cf][k2 + 8] = muv[1];
        p_s[cf][k2]      = pv[0];
        p_s[cf][k2 + 8]  = pv[1];
        if (k2 == 0)
            A_s[cf] = __logf(aout) - 0.5f * tpart - 8.0f * LN2PI;
    }
    __syncthreads();

    float muh[16], ph[16], Ac = 0.f;
    if constexpr (!FIRST) {
        #pragma unroll
        for (int il = 0; il < 16; ++il) { muh[il] = mu_s[c][il]; ph[il] = p_s[c][il]; }
        Ac = A_s[c];
    }

    float S1[16], S2[16], Racc = 0.f;
    #pragma unroll
    for (int i = 0; i < 16; ++i) { S1[i] = 0.f; S2[i] = 0.f; }

    const float4* W4 = (const float4*)W;

    for (int s = 0; s < NSTEP; ++s) {
        const int n_l = wv * (NCAP / 4) + 2 * s + half;
        const int n_g = ch * NCAP + n_l;

        float wreg[16], preg[16];
        {
            const float4* wp = W4 + (size_t)(n_g * 32 + c) * 4;
            float4 w0 = wp[0], w1 = wp[1], w2 = wp[2], w3 = wp[3];
            wreg[0]=w0.x; wreg[1]=w0.y; wreg[2]=w0.z; wreg[3]=w0.w;
            wreg[4]=w1.x; wreg[5]=w1.y; wreg[6]=w1.z; wreg[7]=w1.w;
            wreg[8]=w2.x; wreg[9]=w2.y; wreg[10]=w2.z; wreg[11]=w2.w;
            wreg[12]=w3.x; wreg[13]=w3.y; wreg[14]=w3.z; wreg[15]=w3.w;
            const float4* pp = (const float4*)&pose_s[n_l * 16];
            float4 p0 = pp[0], p1 = pp[1], p2 = pp[2], p3 = pp[3];
            preg[0]=p0.x; preg[1]=p0.y; preg[2]=p0.z; preg[3]=p0.w;
            preg[4]=p1.x; preg[5]=p1.y; preg[6]=p1.z; preg[7]=p1.w;
            preg[8]=p2.x; preg[9]=p2.y; preg[10]=p2.z; preg[11]=p2.w;
            preg[12]=p3.x; preg[13]=p3.y; preg[14]=p3.z; preg[15]=p3.w;
        }

        float v[16];
        #pragma unroll
        for (int i = 0; i < 4; ++i) {
            #pragma unroll
            for (int l = 0; l < 4; ++l) {
                float acc = preg[i*4+0] * wreg[l];
                acc = fmaf(preg[i*4+1], wreg[4 + l], acc);
                acc = fmaf(preg[i*4+2], wreg[8 + l], acc);
                acc = fmaf(preg[i*4+3], wreg[12 + l], acc);
                v[i*4+l] = acc;
            }
        }

        float r;
        if constexpr (FIRST) {
            r = ain_s[n_l] * 0.03125f;      // a_in / C
        } else {
            float acc = 0.0f;
            #pragma unroll
            for (int il = 0; il < 16; ++il) {
                float d = v[il] - muh[il];
                acc = fmaf(-ph[il], d * d, acc);
            }
            float lnap = Ac + acc;
            float m = lnap;
            #pragma unroll
            for (int mk = 16; mk >= 1; mk >>= 1)
                m = fmaxf(m, __shfl_xor(m, mk));
            float e = __expf(lnap - m);
            float ssum = e;
            #pragma unroll
            for (int mk = 16; mk >= 1; mk >>= 1)
                ssum += __shfl_xor(ssum, mk);
            r = __fdividef(e, ssum);
        }

        Racc += r;
        #pragma unroll
        for (int il = 0; il < 16; ++il) {
            float rv = r * v[il];
            S1[il] += rv;
            S2[il] = fmaf(rv, v[il], S2[il]);
        }
    }

    // combine half-wave partials (same c, disjoint n)
    #pragma unroll
    for (int il = 0; il < 16; ++il) {
        S1[il] += __shfl_xor(S1[il], 32);
        S2[il] += __shfl_xor(S2[il], 32);
    }
    Racc += __shfl_xor(Racc, 32);

    if (half == 0) {
        #pragma unroll
        for (int il = 0; il < 16; ++il) {
            S1w[wv][c][il] = S1[il];
            S2w[wv][c][il] = S2[il];
        }
        Rw[wv][c] = Racc;
    }
    __syncthreads();

    // cross-wave reduce + write chunk partial to global
    for (int idx = tid; idx < 512; idx += 256) {
        int c2 = idx >> 4, k = idx & 15;
        float s1 = S1w[0][c2][k] + S1w[1][c2][k] + S1w[2][c2][k] + S1w[3][c2][k];
        float s2 = S2w[0][c2][k] + S2w[1][c2][k] + S2w[2][c2][k] + S2w[3][c2][k];
        size_t base = ((size_t)(pos * NCH + ch) * 32 + c2) * 16 + k;
        part_w[base]        = s1;
        part_w[SZ_S + base] = s2;
    }
    if (tid < 32)
        part_w[2 * (size_t)SZ_S + (pos * NCH + ch) * 32 + tid] =
            Rw[0][tid] + Rw[1][tid] + Rw[2][tid] + Rw[3][tid];
}

// ---------------- final output kernel ----------------
__global__ __launch_bounds__(256)
void em_out(const float* __restrict__ part_r,
            const float* __restrict__ bu,
            const float* __restrict__ ba,
            float* __restrict__ out, int nch)
{
    const int pos = blockIdx.x;
    const int tid = threadIdx.x;
    const int cf = tid >> 3, k2 = tid & 7;
    const int SZ_S = 576 * nch * 512;

    float R = 0.f;
    for (int q = 0; q < nch; ++q)
        R += part_r[2 * (size_t)SZ_S + (pos * nch + q) * 32 + cf];
    float rinv = __fdividef(1.f, R + 1e-8f);
    float muv[2];
    float tpart = 0.f;
    #pragma unroll
    for (int t2 = 0; t2 < 2; ++t2) {
        int k = k2 + t2 * 8;
        int base = ((pos * nch) * 32 + cf) * 16 + k;
        float s1 = 0.f, s2 = 0.f;
        for (int q = 0; q < nch; ++q) {
            s1 += part_r[base + q * 512];
            s2 += part_r[SZ_S + base + q * 512];
        }
        float mu  = s1 * rinv;
        float sig = fmaf(-mu, mu, s2 * rinv);
        sig = fmaxf(sig, 1e-30f);
        muv[t2] = mu;
        tpart  += __logf(sig);
    }
    #pragma unroll
    for (int mk = 4; mk >= 1; mk >>= 1)
        tpart += __shfl_xor(tpart, mk);
    float cost = R * fmaf(0.5f, tpart, 16.f * bu[cf]);
    float aout = __fdividef(1.f, 1.f + __expf(-(0.001f * (ba[cf] - cost))));

    out[(size_t)pos * 512 + cf * 16 + k2]     = muv[0];
    out[(size_t)pos * 512 + cf * 16 + k2 + 8] = muv[1];
    if (k2 == 0)
        out[294912 + pos * 32 + cf] = aout;
}

// ---------------- legacy single-kernel fallback (R1, known-good 107us) ----------------
#define NB 288
#define LNSTEP 36
__global__ __launch_bounds__(256, 2)
void convcaps_em_legacy(const float* __restrict__ x, const float* __restrict__ a,
                        const float* __restrict__ W, const float* __restrict__ bu,
                        const float* __restrict__ ba, float* __restrict__ out)
{
    __shared__ __align__(16) float pose_s[NB * 16];
    __shared__ __align__(16) float ain_s[NB];
    __shared__ float S1w[4][32][17];
    __shared__ float S2w[4][32][17];
    __shared__ float Rw[4][32];
    __shared__ float mu_s[32][17];
    __shared__ float p_s[32][17];
    __shared__ float A_s[32];

    const int tid = threadIdx.x, wv = tid >> 6, lane = tid & 63;
    const int half = (lane >> 5) & 1, c = lane & 31;
    const int bid = blockIdx.x, b = bid / 36, rem = bid % 36;
    const int oy = rem / 6, ox = rem % 6, iy0 = oy * 2, ix0 = ox * 2;
    {
        const float4* x4 = (const float4*)x;
        float4* d4 = (float4*)pose_s;
        for (int idx = tid; idx < 1152; idx += 256) {
            int seg = idx >> 7, u = idx & 127, kh = seg / 3, kw = seg % 3;
            d4[idx] = x4[((b * 14 + iy0 + kh) * 14 + (ix0 + kw)) * 128 + u];
        }
        const float4* a4 = (const float4*)a;
        float4* e4 = (float4*)ain_s;
        if (tid < 72) {
            int seg = tid >> 3, u = tid & 7, kh = seg / 3, kw = seg % 3;
            e4[tid] = a4[((b * 14 + iy0 + kh) * 14 + (ix0 + kw)) * 8 + u];
        }
    }
    __syncthreads();
    const float4* W4 = (const float4*)W;
    float muh[16], ph[16], Ac = 0.0f;
    #pragma unroll
    for (int i = 0; i < 16; ++i) { muh[i] = 0.0f; ph[i] = 0.0f; }
    for (int iter = 0; iter < 3; ++iter) {
        if (iter > 0) {
            #pragma unroll
            for (int il = 0; il < 16; ++il) { muh[il] = mu_s[c][il]; ph[il] = p_s[c][il]; }
            Ac = A_s[c];
        }
        float S1[16], S2[16], Racc = 0.0f;
        #pragma unroll
        for (int i = 0; i < 16; ++i) { S1[i] = 0.0f; S2[i] = 0.0f; }
        for (int s = 0; s < LNSTEP; ++s) {
            const int n = wv * 72 + 2 * s + half;
            float wreg[16], preg[16];
            const float4* wp = W4 + (size_t)(n * 32 + c) * 4;
            float4 w0 = wp[0], w1 = wp[1], w2 = wp[2], w3 = wp[3];
            wreg[0]=w0.x; wreg[1]=w0.y; wreg[2]=w0.z; wreg[3]=w0.w;
            wreg[4]=w1.x; wreg[5]=w1.y; wreg[6]=w1.z; wreg[7]=w1.w;
            wreg[8]=w2.x; wreg[9]=w2.y; wreg[10]=w2.z; wreg[11]=w2.w;
            wreg[12]=w3.x; wreg[13]=w3.y; wreg[14]=w3.z; wreg[15]=w3.w;
            const float4* pp = (const float4*)&pose_s[n * 16];
            float4 p0 = pp[0], p1 = pp[1], p2 = pp[2], p3 = pp[3];
            preg[0]=p0.x; preg[1]=p0.y; preg[2]=p0.z; preg[3]=p0.w;
            preg[4]=p1.x; preg[5]=p1.y; preg[6]=p1.z; preg[7]=p1.w;
            preg[8]=p2.x; preg[9]=p2.y; preg[10]=p2.z; preg[11]=p2.w;
            preg[12]=p3.x; preg[13]=p3.y; preg[14]=p3.z; preg[15]=p3.w;
            float v[16];
            #pragma unroll
            for (int i = 0; i < 4; ++i)
                #pragma unroll
                for (int l = 0; l < 4; ++l) {
                    float acc = preg[i*4+0] * wreg[l];
                    acc = fmaf(preg[i*4+1], wreg[4+l], acc);
                    acc = fmaf(preg[i*4+2], wreg[8+l], acc);
                    acc = fmaf(preg[i*4+3], wreg[12+l], acc);
                    v[i*4+l] = acc;
                }
            float r;
            if (iter == 0) r = ain_s[n] * 0.03125f;
            else {
                float acc = 0.0f;
                #pragma unroll
                for (int il = 0; il < 16; ++il) { float d = v[il]-muh[il]; acc = fmaf(-ph[il], d*d, acc); }
                float lnap = Ac + acc, m = lnap;
                #pragma unroll
                for (int mk = 16; mk >= 1; mk >>= 1) m = fmaxf(m, __shfl_xor(m, mk));
                float e = __expf(lnap - m), ssum = e;
                #pragma unroll
                for (int mk = 16; mk >= 1; mk >>= 1) ssum += __shfl_xor(ssum, mk);
                r = __fdividef(e, ssum);
            }
            Racc += r;
            #pragma unroll
            for (int il = 0; il < 16; ++il) { float rv = r * v[il]; S1[il] += rv; S2[il] = fmaf(rv, v[il], S2[il]); }
        }
        #pragma unroll
        for (int il = 0; il < 16; ++il) { S1[il] += __shfl_xor(S1[il], 32); S2[il] += __shfl_xor(S2[il], 32); }
        Racc += __shfl_xor(Racc, 32);
        if (half == 0) {
            #pragma unroll
            for (int il = 0; il < 16; ++il) { S1w[wv][c][il] = S1[il]; S2w[wv][c][il] = S2[il]; }
            Rw[wv][c] = Racc;
        }
        __syncthreads();
        {
            const int c2 = tid >> 3, k = tid & 7;
            float R = Rw[0][c2] + Rw[1][c2] + Rw[2][c2] + Rw[3][c2];
            float rinv = __fdividef(1.0f, R + 1e-8f);
            float muv[2], pv[2], tpart = 0.0f;
            #pragma unroll
            for (int t2 = 0; t2 < 2; ++t2) {
                int il = k + t2 * 8;
                float s1 = S1w[0][c2][il]+S1w[1][c2][il]+S1w[2][c2][il]+S1w[3][c2][il];
                float s2 = S2w[0][c2][il]+S2w[1][c2][il]+S2w[2][c2][il]+S2w[3][c2][il];
                float mu = s1 * rinv;
                float sig = fmaf(-mu, mu, s2 * rinv);
                sig = fmaxf(sig, 1e-30f);
                muv[t2] = mu; pv[t2] = __fdividef(0.5f, sig); tpart += __logf(sig);
            }
            #pragma unroll
            for (int mk = 4; mk >= 1; mk >>= 1) tpart += __shfl_xor(tpart, mk);
            float cost = R * fmaf(0.5f, tpart, 16.0f * bu[c2]);
            float aout = __fdividef(1.0f, 1.0f + __expf(-(0.001f * (ba[c2] - cost))));
            if (iter < 2) {
                #pragma unroll
                for (int t2 = 0; t2 < 2; ++t2) { int il = k + t2*8; mu_s[c2][il] = muv[t2]; p_s[c2][il] = pv[t2]; }
                if (k == 0) A_s[c2] = __logf(aout) - 0.5f * tpart - 8.0f * LN2PI;
            } else {
                #pragma unroll
                for (int t2 = 0; t2 < 2; ++t2) { int il = k + t2*8; out[(size_t)bid*512 + c2*16 + il] = muv[t2]; }
                if (k == 0) out[294912 + bid * 32 + c2] = aout;
            }
        }
        __syncthreads();
    }
}

// ---------------- host ----------------
template<int NCH>
static void run_split(const float* x, const float* a, const float* w,
                      const float* bu, const float* ba, float* out,
                      float* wsf, hipStream_t stream)
{
    const size_t bufN = (size_t)576 * NCH * 32 * 33;   // floats per parity buffer
    float* buf0 = wsf;
    float* buf1 = wsf + bufN;
    hipLaunchKernelGGL((em_pass<NCH, true>),  dim3(576, NCH), dim3(256), 0, stream,
                       x, a, w, bu, ba, (const float*)nullptr, buf0);
    hipLaunchKernelGGL((em_pass<NCH, false>), dim3(576, NCH), dim3(256), 0, stream,
                       x, a, w, bu, ba, buf0, buf1);
    hipLaunchKernelGGL((em_pass<NCH, false>), dim3(576, NCH), dim3(256), 0, stream,
                       x, a, w, bu, ba, buf1, buf0);
    hipLaunchKernelGGL(em_out, dim3(576), dim3(256), 0, stream, buf0, bu, ba, out, NCH);
}

extern "C" void kernel_launch(void* const* d_in, const int* in_sizes, int n_in,
                              void* d_out, int out_size, void* d_ws, size_t ws_size,
                              hipStream_t stream) {
    (void)in_sizes; (void)n_in; (void)out_size;
    const float* x  = (const float*)d_in[0];
    const float* a  = (const float*)d_in[1];
    const float* w  = (const float*)d_in[2];
    const float* bu = (const float*)d_in[3];
    const float* ba = (const float*)d_in[4];
    float* out = (float*)d_out;
    float* wsf = (float*)d_ws;

    auto need = [](int nch) -> size_t { return (size_t)2 * 576 * nch * 32 * 33 * 4; };

    if (ws_size >= need(4))      run_split<4>(x, a, w, bu, ba, out, wsf, stream);
    else if (ws_size >= need(2)) run_split<2>(x, a, w, bu, ba, out, wsf, stream);
    else if (ws_size >= need(1)) run_split<1>(x, a, w, bu, ba, out, wsf, stream);
    else
        hipLaunchKernelGGL(convcaps_em_legacy, dim3(576), dim3(256), 0, stream,
                           x, a, w, bu, ba, out);
}